// Round 1
// baseline (244.545 us; speedup 1.0000x reference)
//
#include <hip/hip_runtime.h>

#define B_   4
#define S_   4096
#define NC   8192
#define C_   512
#define CS   256
#define KTOT 768

typedef __attribute__((ext_vector_type(8))) short short8;
typedef __attribute__((ext_vector_type(4))) float f32x4;

// fp32 -> bf16 round-to-nearest-even (finite inputs only)
static __device__ __forceinline__ unsigned short f2bf(float x) {
    unsigned u = __builtin_bit_cast(unsigned, x);
    unsigned r = u + 0x7FFFu + ((u >> 16) & 1u);
    return (unsigned short)(r >> 16);
}

// ---------------- K0: pad ref_xyz to float4 with precomputed r2 ----------------
__global__ __launch_bounds__(256) void pad_ref_kernel(const float* __restrict__ rxyz,
                                                      float4* __restrict__ refp) {
    int gid = blockIdx.x * 256 + threadIdx.x;  // 0..32767 (B*NC)
    float x = rxyz[gid * 3 + 0];
    float y = rxyz[gid * 3 + 1];
    float z = rxyz[gid * 3 + 2];
    // r2 = (x*x + y*y) + z*z, no FMA (matches np sum over last axis)
    float r2 = __fadd_rn(__fadd_rn(__fmul_rn(x, x), __fmul_rn(y, y)), __fmul_rn(z, z));
    refp[gid] = make_float4(x, y, z, r2);
}

// ---------------- K1: argmin over Nc, replicating np fp32 rounding ----------------
// block: 256 thr = 32 queries x 8 ref-partitions (1024 refs each)
// grid: (S/32, B)
__global__ __launch_bounds__(256) void argmin_kernel(const float* __restrict__ qxyz,
                                                     const float4* __restrict__ refp,
                                                     int* __restrict__ idxout) {
    int tid = threadIdx.x;
    int b = blockIdx.y;
    int q = tid & 31;
    int p = tid >> 5;
    int s = blockIdx.x * 32 + q;
    const float* qp = qxyz + ((size_t)(b * S_ + s)) * 3;
    float qx = qp[0], qy = qp[1], qz = qp[2];
    float q2 = __fadd_rn(__fadd_rn(__fmul_rn(qx, qx), __fmul_rn(qy, qy)), __fmul_rn(qz, qz));
    const float4* rp = refp + b * NC + p * 1024;
    float best = 3.4028235e38f;
    int bi = 0;
    #pragma unroll 8
    for (int n = 0; n < 1024; ++n) {
        float4 r = rp[n];
        // qr = ((qx*rx + qy*ry) + qz*rz), no FMA
        float qr = __fadd_rn(__fadd_rn(__fmul_rn(qx, r.x), __fmul_rn(qy, r.y)),
                             __fmul_rn(qz, r.z));
        // d2 = (q2 + r2) - (2*qr)   (2*qr exact)
        float d2 = __fsub_rn(__fadd_rn(q2, r.w), __fadd_rn(qr, qr));
        if (d2 < best) { best = d2; bi = n; }   // strict <: first occurrence
    }
    __shared__ float sb[8][32];
    __shared__ int   si[8][32];
    sb[p][q] = best;
    si[p][q] = p * 1024 + bi;
    __syncthreads();
    if (tid < 32) {
        float bv = sb[0][tid];
        int bx = si[0][tid];
        #pragma unroll
        for (int pp = 1; pp < 8; ++pp) {
            float v = sb[pp][tid];
            if (v < bv) { bv = v; bx = si[pp][tid]; }  // ascending p: keeps lowest index on ties
        }
        idxout[b * S_ + blockIdx.x * 32 + tid] = bx;
    }
}

// ---------------- K2: transpose ref_feat (B,C,Nc) fp32 -> refT (B,Nc,C) bf16 ----------------
// grid: (Nc/64, C/64, B), block 256
__global__ __launch_bounds__(256) void transpose_kernel(const float* __restrict__ rf,
                                                        unsigned short* __restrict__ refT) {
    __shared__ float t[64][65];   // [n][c], padded
    int tid = threadIdx.x;
    int b = blockIdx.z;
    int c0 = blockIdx.y * 64;
    int n0 = blockIdx.x * 64;
    int tx = tid & 15, ty = tid >> 4;
    #pragma unroll
    for (int r = 0; r < 4; ++r) {
        int c = r * 16 + ty;
        float4 v = *(const float4*)(rf + ((size_t)b * C_ + c0 + c) * NC + n0 + tx * 4);
        t[tx * 4 + 0][c] = v.x;
        t[tx * 4 + 1][c] = v.y;
        t[tx * 4 + 2][c] = v.z;
        t[tx * 4 + 3][c] = v.w;
    }
    __syncthreads();
    #pragma unroll
    for (int r = 0; r < 4; ++r) {
        int n = r * 16 + ty;
        ushort4 o;
        o.x = f2bf(t[n][tx * 4 + 0]);
        o.y = f2bf(t[n][tx * 4 + 1]);
        o.z = f2bf(t[n][tx * 4 + 2]);
        o.w = f2bf(t[n][tx * 4 + 3]);
        *(ushort4*)(refT + ((size_t)b * NC + n0 + n) * C_ + c0 + tx * 4) = o;
    }
}

// ---------------- K3a: Wc = W_concat[:,256:] @ W_seed  -> Wcomb cols 256..767 (bf16) ----------------
// tiled mini-SGEMM, grid (512/64, 256/64), block 256, each thread 4x4 outputs
__global__ __launch_bounds__(256) void wc_kernel(const float* __restrict__ Wcat,
                                                 const float* __restrict__ Wseed,
                                                 unsigned short* __restrict__ Wcomb) {
    __shared__ float sa[64][68];   // [o][k]
    __shared__ float sbt[64][68];  // [k][c]
    int tid = threadIdx.x;
    int to = blockIdx.y * 64;
    int tc = blockIdx.x * 64;
    int tx = tid & 15, ty = tid >> 4;
    float acc[4][4] = {};
    for (int kt = 0; kt < 256; kt += 64) {
        __syncthreads();
        #pragma unroll
        for (int r = 0; r < 4; ++r) {
            int oo = r * 16 + ty;
            float4 v = *(const float4*)(Wcat + (size_t)(to + oo) * 512 + 256 + kt + tx * 4);
            sa[oo][tx * 4 + 0] = v.x;
            sa[oo][tx * 4 + 1] = v.y;
            sa[oo][tx * 4 + 2] = v.z;
            sa[oo][tx * 4 + 3] = v.w;
            float4 u = *(const float4*)(Wseed + (size_t)(kt + oo) * 512 + tc + tx * 4);
            sbt[oo][tx * 4 + 0] = u.x;
            sbt[oo][tx * 4 + 1] = u.y;
            sbt[oo][tx * 4 + 2] = u.z;
            sbt[oo][tx * 4 + 3] = u.w;
        }
        __syncthreads();
        for (int k = 0; k < 64; ++k) {
            float a[4], bb[4];
            #pragma unroll
            for (int i = 0; i < 4; ++i) a[i] = sa[ty * 4 + i][k];
            #pragma unroll
            for (int j = 0; j < 4; ++j) bb[j] = sbt[k][tx * 4 + j];
            #pragma unroll
            for (int i = 0; i < 4; ++i)
                #pragma unroll
                for (int j = 0; j < 4; ++j)
                    acc[i][j] = fmaf(a[i], bb[j], acc[i][j]);
        }
    }
    #pragma unroll
    for (int i = 0; i < 4; ++i)
        #pragma unroll
        for (int j = 0; j < 4; ++j)
            Wcomb[(size_t)(to + ty * 4 + i) * KTOT + 256 + tc + tx * 4 + j] = f2bf(acc[i][j]);
}

// ---------------- K3b: copy W1 = W_concat[:, :256] -> Wcomb cols 0..255 ----------------
__global__ __launch_bounds__(256) void w1_kernel(const float* __restrict__ Wcat,
                                                 unsigned short* __restrict__ Wcomb) {
    int gid = blockIdx.x * 256 + threadIdx.x;  // 65536
    int o = gid >> 8, c = gid & 255;
    Wcomb[(size_t)o * KTOT + c] = f2bf(Wcat[(size_t)o * 512 + c]);
}

// ---------------- K3c: b_eff = W2 @ b_seed + b_concat ----------------
__global__ __launch_bounds__(256) void beff_kernel(const float* __restrict__ Wcat,
                                                   const float* __restrict__ bseed,
                                                   const float* __restrict__ bcat,
                                                   float* __restrict__ beff) {
    int o = threadIdx.x;
    float acc = bcat[o];
    #pragma unroll 8
    for (int j = 0; j < 256; ++j)
        acc = fmaf(Wcat[(size_t)o * 512 + 256 + j], bseed[j], acc);
    beff[o] = acc;
}

// ---------------- K4: fused gather + GEMM ----------------
// out[b](256 x 4096) = Wcomb(256 x 768) @ X(768 x 4096) + b_eff
// X rows 0..255  = seed_features[b] (fp32->bf16 on stage)
// X rows 256..767 = refT[b, idx[b,s], :] (bf16 row gather)
// block tile 256(M) x 64(N), BK=32, 4 waves each 64x64. grid (S/64, B)
__global__ __launch_bounds__(256) void fused_gemm_kernel(
        const unsigned short* __restrict__ Wcomb,
        const float* __restrict__ seed,
        const unsigned short* __restrict__ refT,
        const int* __restrict__ idx,
        const float* __restrict__ beff,
        float* __restrict__ out) {
    __shared__ __align__(16) unsigned short sA[256][40];  // [m][kk], pad 40 (2-way free)
    __shared__ __align__(16) unsigned short sB[64][40];   // [n][kk]
    __shared__ int sIdx[64];
    __shared__ float sBias[256];

    int tid = threadIdx.x;
    int b = blockIdx.y;
    int s0 = blockIdx.x * 64;
    if (tid < 64) sIdx[tid] = idx[b * S_ + s0 + tid];
    sBias[tid] = beff[tid];

    int lane = tid & 63;
    int w = tid >> 6;
    int ln = lane & 15;
    int quad = lane >> 4;
    int q8 = quad * 8;

    f32x4 acc[4][4];
    #pragma unroll
    for (int i = 0; i < 4; ++i)
        #pragma unroll
        for (int j = 0; j < 4; ++j)
            acc[i][j] = (f32x4){0.f, 0.f, 0.f, 0.f};

    for (int ks = 0; ks < 24; ++ks) {
        int k0 = ks * 32;
        __syncthreads();
        // stage A: 256x32 bf16, 8 chunks of ushort4 per thread
        #pragma unroll
        for (int i = 0; i < 8; ++i) {
            int chunk = tid + 256 * i;
            int mm = chunk >> 3;
            int kk4 = (chunk & 7) << 2;
            ushort4 v = *(const ushort4*)(Wcomb + (size_t)mm * KTOT + k0 + kk4);
            *(ushort4*)&sA[mm][kk4] = v;
        }
        // stage B: 64 cols x 32 k
        if (k0 < 256) {
            #pragma unroll
            for (int i = 0; i < 2; ++i) {
                int chunk = tid + 256 * i;
                int n = chunk >> 3;
                int kk4 = (chunk & 7) << 2;
                const float* sp = seed + ((size_t)b * CS + k0 + kk4) * S_ + s0 + n;
                ushort4 v;
                v.x = f2bf(sp[0]);
                v.y = f2bf(sp[S_]);
                v.z = f2bf(sp[2 * S_]);
                v.w = f2bf(sp[3 * S_]);
                *(ushort4*)&sB[n][kk4] = v;
            }
        } else {
            int koff = k0 - 256;
            #pragma unroll
            for (int i = 0; i < 2; ++i) {
                int chunk = tid + 256 * i;
                int n = chunk >> 3;
                int kk4 = (chunk & 7) << 2;
                const unsigned short* gp =
                    refT + ((size_t)b * NC + sIdx[n]) * C_ + koff + kk4;
                *(ushort4*)&sB[n][kk4] = *(const ushort4*)gp;
            }
        }
        __syncthreads();
        short8 af[4], bf[4];
        #pragma unroll
        for (int i = 0; i < 4; ++i)
            af[i] = *(const short8*)&sA[w * 64 + i * 16 + ln][q8];
        #pragma unroll
        for (int j = 0; j < 4; ++j)
            bf[j] = *(const short8*)&sB[j * 16 + ln][q8];
        #pragma unroll
        for (int i = 0; i < 4; ++i)
            #pragma unroll
            for (int j = 0; j < 4; ++j)
                acc[i][j] = __builtin_amdgcn_mfma_f32_16x16x32_bf16(af[i], bf[j], acc[i][j], 0, 0, 0);
    }

    // epilogue: D layout col=lane&15, row=quad*4+reg
    #pragma unroll
    for (int i = 0; i < 4; ++i) {
        int mb = w * 64 + i * 16 + quad * 4;
        #pragma unroll
        for (int j = 0; j < 4; ++j) {
            int col = s0 + j * 16 + ln;
            #pragma unroll
            for (int r = 0; r < 4; ++r) {
                int m = mb + r;
                out[((size_t)b * CS + m) * S_ + col] = acc[i][j][r] + sBias[m];
            }
        }
    }
}

extern "C" void kernel_launch(void* const* d_in, const int* in_sizes, int n_in,
                              void* d_out, int out_size, void* d_ws, size_t ws_size,
                              hipStream_t stream) {
    const float* qxyz  = (const float*)d_in[0];
    const float* rxyz  = (const float*)d_in[1];
    const float* rfeat = (const float*)d_in[2];
    const float* seed  = (const float*)d_in[3];
    const float* Wseed = (const float*)d_in[4];
    const float* bseed = (const float*)d_in[5];
    const float* Wcat  = (const float*)d_in[6];
    const float* bcat  = (const float*)d_in[7];
    float* out = (float*)d_out;

    char* ws = (char*)d_ws;
    float4* refp          = (float4*)(ws);                       // 512 KB
    int* idxbuf           = (int*)(ws + 524288);                 // 64 KB
    float* beff           = (float*)(ws + 589824);               // 1 KB
    unsigned short* Wcomb = (unsigned short*)(ws + 590848);      // 384 KB
    unsigned short* refT  = (unsigned short*)(ws + 984064);      // 32 MB

    hipLaunchKernelGGL(pad_ref_kernel,   dim3(128),         dim3(256), 0, stream, rxyz, refp);
    hipLaunchKernelGGL(argmin_kernel,    dim3(128, 4),      dim3(256), 0, stream, qxyz, refp, idxbuf);
    hipLaunchKernelGGL(transpose_kernel, dim3(128, 8, 4),   dim3(256), 0, stream, rfeat, refT);
    hipLaunchKernelGGL(wc_kernel,        dim3(8, 4),        dim3(256), 0, stream, Wcat, Wseed, Wcomb);
    hipLaunchKernelGGL(w1_kernel,        dim3(256),         dim3(256), 0, stream, Wcat, Wcomb);
    hipLaunchKernelGGL(beff_kernel,      dim3(1),           dim3(256), 0, stream, Wcat, bseed, bcat, beff);
    hipLaunchKernelGGL(fused_gemm_kernel, dim3(64, 4),      dim3(256), 0, stream,
                       Wcomb, seed, refT, idxbuf, beff, out);
}

// Round 2
// 235.539 us; speedup vs baseline: 1.0382x; 1.0382x over previous
//
#include <hip/hip_runtime.h>

#define B_   4
#define S_   4096
#define NC   8192
#define C_   512
#define CS   256
#define KTOT 768

typedef __attribute__((ext_vector_type(8))) short short8;
typedef __attribute__((ext_vector_type(4))) float f32x4;
typedef float v2f __attribute__((ext_vector_type(2)));

// fp32 -> bf16 round-to-nearest-even (finite inputs only)
static __device__ __forceinline__ unsigned short f2bf(float x) {
    unsigned u = __builtin_bit_cast(unsigned, x);
    unsigned r = u + 0x7FFFu + ((u >> 16) & 1u);
    return (unsigned short)(r >> 16);
}

// Packed fp32 (VOP3P) — IEEE rounding identical to scalar v_mul/v_add/v_sub.
static __device__ __forceinline__ v2f pk_mul(v2f a, v2f b) {
    v2f d;
    asm("v_pk_mul_f32 %0, %1, %2" : "=v"(d) : "v"(a), "v"(b));
    return d;
}
static __device__ __forceinline__ v2f pk_add(v2f a, v2f b) {
    v2f d;
    asm("v_pk_add_f32 %0, %1, %2" : "=v"(d) : "v"(a), "v"(b));
    return d;
}
static __device__ __forceinline__ v2f pk_sub(v2f a, v2f b) {
    v2f d;
    asm("v_pk_add_f32 %0, %1, %2 neg_lo:[0,1] neg_hi:[0,1]" : "=v"(d) : "v"(a), "v"(b));
    return d;
}

// ---------------- K0: pack ref pairs SoA: {x0,x1,y0,y1} {z0,z1,r20,r21} ----------------
__global__ __launch_bounds__(256) void pad_ref_kernel(const float* __restrict__ rxyz,
                                                      float4* __restrict__ refpk) {
    int gid = blockIdx.x * 256 + threadIdx.x;  // 0..16383 (B*NC/2)
    int b = gid >> 12;
    int pr = gid & 4095;
    const float* p0 = rxyz + ((size_t)b * NC + pr * 2) * 3;
    float x0 = p0[0], y0 = p0[1], z0 = p0[2];
    float x1 = p0[3], y1 = p0[4], z1 = p0[5];
    float r20 = __fadd_rn(__fadd_rn(__fmul_rn(x0, x0), __fmul_rn(y0, y0)), __fmul_rn(z0, z0));
    float r21 = __fadd_rn(__fadd_rn(__fmul_rn(x1, x1), __fmul_rn(y1, y1)), __fmul_rn(z1, z1));
    refpk[gid * 2 + 0] = make_float4(x0, x1, y0, y1);
    refpk[gid * 2 + 1] = make_float4(z0, z1, r20, r21);
}

// ---------------- K1: argmin, packed-pair streams, np-exact rounding ----------------
// block: 256 thr = 8 queries x 32 partitions (128 pairs = 256 refs each)
// grid: (S/8, B) = (512, 4) -> 8 blocks/CU, 100% wave-slot occupancy
__global__ __launch_bounds__(256) void argmin_kernel(const float* __restrict__ qxyz,
                                                     const float4* __restrict__ refpk,
                                                     int* __restrict__ idxout) {
    int tid = threadIdx.x;
    int b = blockIdx.y;
    int q = tid & 7;
    int p = tid >> 3;
    int s = blockIdx.x * 8 + q;
    const float* qp = qxyz + ((size_t)(b * S_ + s)) * 3;
    float qx = qp[0], qy = qp[1], qz = qp[2];
    float q2 = __fadd_rn(__fadd_rn(__fmul_rn(qx, qx), __fmul_rn(qy, qy)), __fmul_rn(qz, qz));
    v2f qx2 = {qx, qx}, qy2 = {qy, qy}, qz2 = {qz, qz}, q22 = {q2, q2};
    const float4* rp = refpk + ((size_t)b * 4096 + p * 128) * 2;
    float be = 3.4028235e38f, bo = 3.4028235e38f;
    int pe = 0, po = 0;
    #pragma unroll 4
    for (int n = 0; n < 128; ++n) {
        float4 v1 = rp[n * 2 + 0];
        float4 v2 = rp[n * 2 + 1];
        v2f xs = {v1.x, v1.y}, ys = {v1.z, v1.w};
        v2f zs = {v2.x, v2.y}, ws = {v2.z, v2.w};
        // qr = ((qx*rx + qy*ry) + qz*rz), no FMA — matches np einsum reduction
        v2f qr = pk_add(pk_add(pk_mul(qx2, xs), pk_mul(qy2, ys)), pk_mul(qz2, zs));
        // d2 = (q2 + r2) - (qr + qr)
        v2f d2 = pk_sub(pk_add(q22, ws), pk_add(qr, qr));
        if (d2.x < be) { be = d2.x; pe = n; }   // strict <: first occurrence
        if (d2.y < bo) { bo = d2.y; po = n; }
    }
    int base = p * 256;
    int ie = base + pe * 2, io = base + po * 2 + 1;
    float bv; int bx;
    if (bo < be || (bo == be && io < ie)) { bv = bo; bx = io; }
    else                                  { bv = be; bx = ie; }
    __shared__ float sb[32][8];
    __shared__ int   si[32][8];
    sb[p][q] = bv;
    si[p][q] = bx;
    __syncthreads();
    if (tid < 8) {
        float v = sb[0][tid];
        int x = si[0][tid];
        #pragma unroll
        for (int pp = 1; pp < 32; ++pp) {
            float vv = sb[pp][tid];
            if (vv < v) { v = vv; x = si[pp][tid]; }  // ascending p keeps lowest index on ties
        }
        idxout[b * S_ + blockIdx.x * 8 + tid] = x;
    }
}

// ---------------- K2: transpose ref_feat (B,C,Nc) fp32 -> refT (B,Nc,C) bf16 ----------------
__global__ __launch_bounds__(256) void transpose_kernel(const float* __restrict__ rf,
                                                        unsigned short* __restrict__ refT) {
    __shared__ float t[64][65];
    int tid = threadIdx.x;
    int b = blockIdx.z;
    int c0 = blockIdx.y * 64;
    int n0 = blockIdx.x * 64;
    int tx = tid & 15, ty = tid >> 4;
    #pragma unroll
    for (int r = 0; r < 4; ++r) {
        int c = r * 16 + ty;
        float4 v = *(const float4*)(rf + ((size_t)b * C_ + c0 + c) * NC + n0 + tx * 4);
        t[tx * 4 + 0][c] = v.x;
        t[tx * 4 + 1][c] = v.y;
        t[tx * 4 + 2][c] = v.z;
        t[tx * 4 + 3][c] = v.w;
    }
    __syncthreads();
    #pragma unroll
    for (int r = 0; r < 4; ++r) {
        int n = r * 16 + ty;
        ushort4 o;
        o.x = f2bf(t[n][tx * 4 + 0]);
        o.y = f2bf(t[n][tx * 4 + 1]);
        o.z = f2bf(t[n][tx * 4 + 2]);
        o.w = f2bf(t[n][tx * 4 + 3]);
        *(ushort4*)(refT + ((size_t)b * NC + n0 + n) * C_ + c0 + tx * 4) = o;
    }
}

// ---------------- K3a: Wc = W_concat[:,256:] @ W_seed -> Wcomb cols 256..767 ----------------
__global__ __launch_bounds__(256) void wc_kernel(const float* __restrict__ Wcat,
                                                 const float* __restrict__ Wseed,
                                                 unsigned short* __restrict__ Wcomb) {
    __shared__ float sa[64][68];
    __shared__ float sbt[64][68];
    int tid = threadIdx.x;
    int to = blockIdx.y * 64;
    int tc = blockIdx.x * 64;
    int tx = tid & 15, ty = tid >> 4;
    float acc[4][4] = {};
    for (int kt = 0; kt < 256; kt += 64) {
        __syncthreads();
        #pragma unroll
        for (int r = 0; r < 4; ++r) {
            int oo = r * 16 + ty;
            float4 v = *(const float4*)(Wcat + (size_t)(to + oo) * 512 + 256 + kt + tx * 4);
            sa[oo][tx * 4 + 0] = v.x;
            sa[oo][tx * 4 + 1] = v.y;
            sa[oo][tx * 4 + 2] = v.z;
            sa[oo][tx * 4 + 3] = v.w;
            float4 u = *(const float4*)(Wseed + (size_t)(kt + oo) * 512 + tc + tx * 4);
            sbt[oo][tx * 4 + 0] = u.x;
            sbt[oo][tx * 4 + 1] = u.y;
            sbt[oo][tx * 4 + 2] = u.z;
            sbt[oo][tx * 4 + 3] = u.w;
        }
        __syncthreads();
        for (int k = 0; k < 64; ++k) {
            float a[4], bb[4];
            #pragma unroll
            for (int i = 0; i < 4; ++i) a[i] = sa[ty * 4 + i][k];
            #pragma unroll
            for (int j = 0; j < 4; ++j) bb[j] = sbt[k][tx * 4 + j];
            #pragma unroll
            for (int i = 0; i < 4; ++i)
                #pragma unroll
                for (int j = 0; j < 4; ++j)
                    acc[i][j] = fmaf(a[i], bb[j], acc[i][j]);
        }
    }
    #pragma unroll
    for (int i = 0; i < 4; ++i)
        #pragma unroll
        for (int j = 0; j < 4; ++j)
            Wcomb[(size_t)(to + ty * 4 + i) * KTOT + 256 + tc + tx * 4 + j] = f2bf(acc[i][j]);
}

// ---------------- K3b: W1 = W_concat[:, :256] -> Wcomb cols 0..255 ----------------
__global__ __launch_bounds__(256) void w1_kernel(const float* __restrict__ Wcat,
                                                 unsigned short* __restrict__ Wcomb) {
    int gid = blockIdx.x * 256 + threadIdx.x;  // 65536
    int o = gid >> 8, c = gid & 255;
    Wcomb[(size_t)o * KTOT + c] = f2bf(Wcat[(size_t)o * 512 + c]);
}

// ---------------- K3c: b_eff = W2 @ b_seed + b_concat ----------------
__global__ __launch_bounds__(256) void beff_kernel(const float* __restrict__ Wcat,
                                                   const float* __restrict__ bseed,
                                                   const float* __restrict__ bcat,
                                                   float* __restrict__ beff) {
    int o = threadIdx.x;
    float acc = bcat[o];
    #pragma unroll 8
    for (int j = 0; j < 256; ++j)
        acc = fmaf(Wcat[(size_t)o * 512 + 256 + j], bseed[j], acc);
    beff[o] = acc;
}

// ---------------- K4: fused gather + GEMM ----------------
// out[b](256 x 4096) = Wcomb(256x768) @ X(768x4096) + b_eff
// block tile 128(M) x 32(N), BK=64, 4 waves (each 32M x 32N). grid (128, 2, 4)
__global__ __launch_bounds__(256) void fused_gemm_kernel(
        const unsigned short* __restrict__ Wcomb,
        const float* __restrict__ seed,
        const unsigned short* __restrict__ refT,
        const int* __restrict__ idx,
        const float* __restrict__ beff,
        float* __restrict__ out) {
    __shared__ __align__(16) unsigned short sA[128][72];  // [m][kk], pad 72
    __shared__ __align__(16) unsigned short sB[32][72];   // [n][kk]
    __shared__ int sIdx[32];
    __shared__ float sBias[128];

    int tid = threadIdx.x;
    int b = blockIdx.z;
    int m0 = blockIdx.y * 128;
    int s0 = blockIdx.x * 32;
    if (tid < 32) sIdx[tid] = idx[b * S_ + s0 + tid];
    if (tid < 128) sBias[tid] = beff[m0 + tid];

    int lane = tid & 63;
    int w = tid >> 6;
    int ln = lane & 15;
    int quad = lane >> 4;
    int q8 = quad * 8;

    f32x4 acc[2][2];
    #pragma unroll
    for (int i = 0; i < 2; ++i)
        #pragma unroll
        for (int j = 0; j < 2; ++j)
            acc[i][j] = (f32x4){0.f, 0.f, 0.f, 0.f};

    for (int ks = 0; ks < 12; ++ks) {
        int k0 = ks * 64;
        __syncthreads();
        // stage A: 128x64 bf16, 4 chunks of 16B per thread
        #pragma unroll
        for (int i = 0; i < 4; ++i) {
            int ch = tid + 256 * i;
            int mm = ch >> 3;
            int kk8 = (ch & 7) << 3;
            *(short8*)&sA[mm][kk8] =
                *(const short8*)(Wcomb + (size_t)(m0 + mm) * KTOT + k0 + kk8);
        }
        // stage B: 32 cols x 64 k, 1 chunk of 16B-equivalent per thread
        if (k0 < 256) {
            // seed fp32 -> bf16 convert; thread = (kgrp, n) for coalescing over n
            int n = tid & 31;
            int kk8 = (tid >> 5) << 3;
            const float* sp = seed + ((size_t)b * CS + k0 + kk8) * S_ + s0 + n;
            unsigned short tmp[8];
            #pragma unroll
            for (int r = 0; r < 8; ++r)
                tmp[r] = f2bf(sp[(size_t)r * S_]);
            *(short8*)&sB[n][kk8] = *(const short8*)tmp;
        } else {
            int n = tid >> 3;
            int kk8 = (tid & 7) << 3;
            const unsigned short* gp =
                refT + ((size_t)b * NC + sIdx[n]) * C_ + (k0 - 256) + kk8;
            *(short8*)&sB[n][kk8] = *(const short8*)gp;
        }
        __syncthreads();
        #pragma unroll
        for (int kf = 0; kf < 2; ++kf) {
            short8 af[2], bfr[2];
            #pragma unroll
            for (int i = 0; i < 2; ++i)
                af[i] = *(const short8*)&sA[w * 32 + i * 16 + ln][kf * 32 + q8];
            #pragma unroll
            for (int j = 0; j < 2; ++j)
                bfr[j] = *(const short8*)&sB[j * 16 + ln][kf * 32 + q8];
            #pragma unroll
            for (int i = 0; i < 2; ++i)
                #pragma unroll
                for (int j = 0; j < 2; ++j)
                    acc[i][j] = __builtin_amdgcn_mfma_f32_16x16x32_bf16(af[i], bfr[j], acc[i][j], 0, 0, 0);
        }
    }

    // epilogue: D layout col=lane&15, row=quad*4+reg
    #pragma unroll
    for (int i = 0; i < 2; ++i) {
        int mb = w * 32 + i * 16 + quad * 4;
        #pragma unroll
        for (int j = 0; j < 2; ++j) {
            int col = s0 + j * 16 + ln;
            #pragma unroll
            for (int r = 0; r < 4; ++r) {
                int m = mb + r;
                out[((size_t)b * CS + m0 + m) * S_ + col] = acc[i][j][r] + sBias[m];
            }
        }
    }
}

extern "C" void kernel_launch(void* const* d_in, const int* in_sizes, int n_in,
                              void* d_out, int out_size, void* d_ws, size_t ws_size,
                              hipStream_t stream) {
    const float* qxyz  = (const float*)d_in[0];
    const float* rxyz  = (const float*)d_in[1];
    const float* rfeat = (const float*)d_in[2];
    const float* seed  = (const float*)d_in[3];
    const float* Wseed = (const float*)d_in[4];
    const float* bseed = (const float*)d_in[5];
    const float* Wcat  = (const float*)d_in[6];
    const float* bcat  = (const float*)d_in[7];
    float* out = (float*)d_out;

    char* ws = (char*)d_ws;
    float4* refpk         = (float4*)(ws);                       // 512 KB
    int* idxbuf           = (int*)(ws + 524288);                 // 64 KB
    float* beff           = (float*)(ws + 589824);               // 1 KB
    unsigned short* Wcomb = (unsigned short*)(ws + 590848);      // 384 KB
    unsigned short* refT  = (unsigned short*)(ws + 984064);      // 32 MB

    hipLaunchKernelGGL(pad_ref_kernel,    dim3(64),          dim3(256), 0, stream, rxyz, refpk);
    hipLaunchKernelGGL(argmin_kernel,     dim3(512, 4),      dim3(256), 0, stream, qxyz, refpk, idxbuf);
    hipLaunchKernelGGL(transpose_kernel,  dim3(128, 8, 4),   dim3(256), 0, stream, rfeat, refT);
    hipLaunchKernelGGL(wc_kernel,         dim3(8, 4),        dim3(256), 0, stream, Wcat, Wseed, Wcomb);
    hipLaunchKernelGGL(w1_kernel,         dim3(256),         dim3(256), 0, stream, Wcat, Wcomb);
    hipLaunchKernelGGL(beff_kernel,       dim3(1),           dim3(256), 0, stream, Wcat, bseed, bcat, beff);
    hipLaunchKernelGGL(fused_gemm_kernel, dim3(128, 2, 4),   dim3(256), 0, stream,
                       Wcomb, seed, refT, idxbuf, beff, out);
}

// Round 3
// 221.856 us; speedup vs baseline: 1.1023x; 1.0617x over previous
//
#include <hip/hip_runtime.h>

#define B_   4
#define S_   4096
#define NC   8192
#define C_   512
#define CS   256
#define KTOT 768
#define NPAIR 4096   // NC/2 pairs per batch

typedef __attribute__((ext_vector_type(8))) short short8;
typedef __attribute__((ext_vector_type(4))) float f32x4;
typedef float v2f __attribute__((ext_vector_type(2)));

// fp32 -> bf16 round-to-nearest-even (finite inputs only)
static __device__ __forceinline__ unsigned short f2bf(float x) {
    unsigned u = __builtin_bit_cast(unsigned, x);
    unsigned r = u + 0x7FFFu + ((u >> 16) & 1u);
    return (unsigned short)(r >> 16);
}

// Packed fp32 (VOP3P) — IEEE rounding identical to scalar v_mul/v_add/v_sub.
static __device__ __forceinline__ v2f pk_mul(v2f a, v2f b) {
    v2f d;
    asm("v_pk_mul_f32 %0, %1, %2" : "=v"(d) : "v"(a), "v"(b));
    return d;
}
static __device__ __forceinline__ v2f pk_add(v2f a, v2f b) {
    v2f d;
    asm("v_pk_add_f32 %0, %1, %2" : "=v"(d) : "v"(a), "v"(b));
    return d;
}
static __device__ __forceinline__ v2f pk_sub(v2f a, v2f b) {
    v2f d;
    asm("v_pk_add_f32 %0, %1, %2 neg_lo:[0,1] neg_hi:[0,1]" : "=v"(d) : "v"(a), "v"(b));
    return d;
}

// ---------------- K0: pack ref pairs, two SoA planes ----------------
// plane1[b*NPAIR+p] = {x0,x1,y0,y1}; plane2[b*NPAIR+p] = {z0,z1,r20,r21}
__global__ __launch_bounds__(256) void pad_ref_kernel(const float* __restrict__ rxyz,
                                                      float4* __restrict__ refpk) {
    int gid = blockIdx.x * 256 + threadIdx.x;  // 0..16383 (B*NPAIR)
    int b = gid >> 12;
    int pr = gid & 4095;
    const float* p0 = rxyz + ((size_t)b * NC + pr * 2) * 3;
    float x0 = p0[0], y0 = p0[1], z0 = p0[2];
    float x1 = p0[3], y1 = p0[4], z1 = p0[5];
    float r20 = __fadd_rn(__fadd_rn(__fmul_rn(x0, x0), __fmul_rn(y0, y0)), __fmul_rn(z0, z0));
    float r21 = __fadd_rn(__fadd_rn(__fmul_rn(x1, x1), __fmul_rn(y1, y1)), __fmul_rn(z1, z1));
    refpk[gid]                = make_float4(x0, x1, y0, y1);
    refpk[B_ * NPAIR + gid]   = make_float4(z0, z1, r20, r21);
}

// ---------------- K1: argmin — queries in regs, refs distinct per lane ----------------
// block 256 = 4 waves; wave qg holds 8 queries (replicated per lane); lane scans
// pairs {j*64+lane : j=0..63} — coalesced, zero duplication. grid (S/32, B).
__global__ __launch_bounds__(256) void argmin_kernel(const float* __restrict__ qxyz,
                                                     const float4* __restrict__ refpk,
                                                     int* __restrict__ idxout) {
    int tid = threadIdx.x;
    int lane = tid & 63;
    int qg = tid >> 6;
    int b = blockIdx.y;
    int sbase = blockIdx.x * 32 + qg * 8;

    v2f qx2[8], qy2[8], qz2[8], q22[8];
    #pragma unroll
    for (int q = 0; q < 8; ++q) {
        const float* qp = qxyz + ((size_t)(b * S_ + sbase + q)) * 3;
        float qx = qp[0], qy = qp[1], qz = qp[2];
        float q2 = __fadd_rn(__fadd_rn(__fmul_rn(qx, qx), __fmul_rn(qy, qy)),
                             __fmul_rn(qz, qz));
        qx2[q] = (v2f){qx, qx};
        qy2[q] = (v2f){qy, qy};
        qz2[q] = (v2f){qz, qz};
        q22[q] = (v2f){q2, q2};
    }

    const float4* p1 = refpk + (size_t)b * NPAIR + lane;
    const float4* p2 = p1 + (size_t)B_ * NPAIR;

    float be[8], bo[8];
    int pe[8], po[8];
    #pragma unroll
    for (int q = 0; q < 8; ++q) {
        be[q] = 3.4028235e38f; bo[q] = 3.4028235e38f; pe[q] = 0; po[q] = 0;
    }

    #pragma unroll 2
    for (int j = 0; j < 64; ++j) {
        float4 v1 = p1[j * 64];
        float4 v2 = p2[j * 64];
        v2f xs = {v1.x, v1.y}, ys = {v1.z, v1.w};
        v2f zs = {v2.x, v2.y}, ws = {v2.z, v2.w};
        #pragma unroll
        for (int q = 0; q < 8; ++q) {
            // qr = ((qx*rx + qy*ry) + qz*rz), no FMA — np einsum association
            v2f qr = pk_add(pk_add(pk_mul(qx2[q], xs), pk_mul(qy2[q], ys)),
                            pk_mul(qz2[q], zs));
            // d2 = (q2 + r2) - (qr + qr)
            v2f d2 = pk_sub(pk_add(q22[q], ws), pk_add(qr, qr));
            if (d2.x < be[q]) { be[q] = d2.x; pe[q] = j; }   // strict <: first occurrence
            if (d2.y < bo[q]) { bo[q] = d2.y; po[q] = j; }
        }
    }

    __shared__ float sval[32][64];
    __shared__ int   sidx[32][64];
    #pragma unroll
    for (int q = 0; q < 8; ++q) {
        int ie = ((pe[q] * 64 + lane) << 1);
        int io = ((po[q] * 64 + lane) << 1) | 1;
        float bv; int bx;
        if (bo[q] < be[q] || (bo[q] == be[q] && io < ie)) { bv = bo[q]; bx = io; }
        else                                              { bv = be[q]; bx = ie; }
        sval[qg * 8 + q][lane] = bv;
        sidx[qg * 8 + q][lane] = bx;
    }
    __syncthreads();
    if (tid < 32) {
        float v = sval[tid][0];
        int x = sidx[tid][0];
        #pragma unroll 8
        for (int l = 1; l < 64; ++l) {
            float vv = sval[tid][l];
            int xx = sidx[tid][l];
            // interleaved partitions: must tiebreak on index for first-occurrence
            if (vv < v || (vv == v && xx < x)) { v = vv; x = xx; }
        }
        idxout[b * S_ + blockIdx.x * 32 + tid] = x;
    }
}

// ---------------- K2: transpose ref_feat (B,C,Nc) fp32 -> refT (B,Nc,C) bf16 ----------------
__global__ __launch_bounds__(256) void transpose_kernel(const float* __restrict__ rf,
                                                        unsigned short* __restrict__ refT) {
    __shared__ float t[64][65];
    int tid = threadIdx.x;
    int b = blockIdx.z;
    int c0 = blockIdx.y * 64;
    int n0 = blockIdx.x * 64;
    int tx = tid & 15, ty = tid >> 4;
    #pragma unroll
    for (int r = 0; r < 4; ++r) {
        int c = r * 16 + ty;
        float4 v = *(const float4*)(rf + ((size_t)b * C_ + c0 + c) * NC + n0 + tx * 4);
        t[tx * 4 + 0][c] = v.x;
        t[tx * 4 + 1][c] = v.y;
        t[tx * 4 + 2][c] = v.z;
        t[tx * 4 + 3][c] = v.w;
    }
    __syncthreads();
    #pragma unroll
    for (int r = 0; r < 4; ++r) {
        int n = r * 16 + ty;
        ushort4 o;
        o.x = f2bf(t[n][tx * 4 + 0]);
        o.y = f2bf(t[n][tx * 4 + 1]);
        o.z = f2bf(t[n][tx * 4 + 2]);
        o.w = f2bf(t[n][tx * 4 + 3]);
        *(ushort4*)(refT + ((size_t)b * NC + n0 + n) * C_ + c0 + tx * 4) = o;
    }
}

// ---------------- K3a: Wc = W_concat[:,256:] @ W_seed -> Wcomb cols 256..767 ----------------
__global__ __launch_bounds__(256) void wc_kernel(const float* __restrict__ Wcat,
                                                 const float* __restrict__ Wseed,
                                                 unsigned short* __restrict__ Wcomb) {
    __shared__ float sa[64][68];
    __shared__ float sbt[64][68];
    int tid = threadIdx.x;
    int to = blockIdx.y * 64;
    int tc = blockIdx.x * 64;
    int tx = tid & 15, ty = tid >> 4;
    float acc[4][4] = {};
    for (int kt = 0; kt < 256; kt += 64) {
        __syncthreads();
        #pragma unroll
        for (int r = 0; r < 4; ++r) {
            int oo = r * 16 + ty;
            float4 v = *(const float4*)(Wcat + (size_t)(to + oo) * 512 + 256 + kt + tx * 4);
            sa[oo][tx * 4 + 0] = v.x;
            sa[oo][tx * 4 + 1] = v.y;
            sa[oo][tx * 4 + 2] = v.z;
            sa[oo][tx * 4 + 3] = v.w;
            float4 u = *(const float4*)(Wseed + (size_t)(kt + oo) * 512 + tc + tx * 4);
            sbt[oo][tx * 4 + 0] = u.x;
            sbt[oo][tx * 4 + 1] = u.y;
            sbt[oo][tx * 4 + 2] = u.z;
            sbt[oo][tx * 4 + 3] = u.w;
        }
        __syncthreads();
        for (int k = 0; k < 64; ++k) {
            float a[4], bb[4];
            #pragma unroll
            for (int i = 0; i < 4; ++i) a[i] = sa[ty * 4 + i][k];
            #pragma unroll
            for (int j = 0; j < 4; ++j) bb[j] = sbt[k][tx * 4 + j];
            #pragma unroll
            for (int i = 0; i < 4; ++i)
                #pragma unroll
                for (int j = 0; j < 4; ++j)
                    acc[i][j] = fmaf(a[i], bb[j], acc[i][j]);
        }
    }
    #pragma unroll
    for (int i = 0; i < 4; ++i)
        #pragma unroll
        for (int j = 0; j < 4; ++j)
            Wcomb[(size_t)(to + ty * 4 + i) * KTOT + 256 + tc + tx * 4 + j] = f2bf(acc[i][j]);
}

// ---------------- K3b: W1 = W_concat[:, :256] -> Wcomb cols 0..255 ----------------
__global__ __launch_bounds__(256) void w1_kernel(const float* __restrict__ Wcat,
                                                 unsigned short* __restrict__ Wcomb) {
    int gid = blockIdx.x * 256 + threadIdx.x;  // 65536
    int o = gid >> 8, c = gid & 255;
    Wcomb[(size_t)o * KTOT + c] = f2bf(Wcat[(size_t)o * 512 + c]);
}

// ---------------- K3c: b_eff = W2 @ b_seed + b_concat ----------------
__global__ __launch_bounds__(256) void beff_kernel(const float* __restrict__ Wcat,
                                                   const float* __restrict__ bseed,
                                                   const float* __restrict__ bcat,
                                                   float* __restrict__ beff) {
    int o = threadIdx.x;
    float acc = bcat[o];
    const float4* wp = (const float4*)(Wcat + (size_t)o * 512 + 256);
    const float4* bp = (const float4*)bseed;
    #pragma unroll 4
    for (int j = 0; j < 64; ++j) {
        float4 w = wp[j];
        float4 bb = bp[j];
        acc = fmaf(w.x, bb.x, acc);
        acc = fmaf(w.y, bb.y, acc);
        acc = fmaf(w.z, bb.z, acc);
        acc = fmaf(w.w, bb.w, acc);
    }
    beff[o] = acc;
}

// ---------------- K4: fused gather + GEMM ----------------
// out[b](256 x 4096) = Wcomb(256x768) @ X(768x4096) + b_eff
// block tile 128(M) x 32(N), BK=64, 4 waves (each 32M x 32N). grid (128, 2, 4)
__global__ __launch_bounds__(256) void fused_gemm_kernel(
        const unsigned short* __restrict__ Wcomb,
        const float* __restrict__ seed,
        const unsigned short* __restrict__ refT,
        const int* __restrict__ idx,
        const float* __restrict__ beff,
        float* __restrict__ out) {
    __shared__ __align__(16) unsigned short sA[128][72];
    __shared__ __align__(16) unsigned short sB[32][72];
    __shared__ int sIdx[32];
    __shared__ float sBias[128];

    int tid = threadIdx.x;
    int b = blockIdx.z;
    int m0 = blockIdx.y * 128;
    int s0 = blockIdx.x * 32;
    if (tid < 32) sIdx[tid] = idx[b * S_ + s0 + tid];
    if (tid < 128) sBias[tid] = beff[m0 + tid];

    int lane = tid & 63;
    int w = tid >> 6;
    int ln = lane & 15;
    int quad = lane >> 4;
    int q8 = quad * 8;

    f32x4 acc[2][2];
    #pragma unroll
    for (int i = 0; i < 2; ++i)
        #pragma unroll
        for (int j = 0; j < 2; ++j)
            acc[i][j] = (f32x4){0.f, 0.f, 0.f, 0.f};

    for (int ks = 0; ks < 12; ++ks) {
        int k0 = ks * 64;
        __syncthreads();
        #pragma unroll
        for (int i = 0; i < 4; ++i) {
            int ch = tid + 256 * i;
            int mm = ch >> 3;
            int kk8 = (ch & 7) << 3;
            *(short8*)&sA[mm][kk8] =
                *(const short8*)(Wcomb + (size_t)(m0 + mm) * KTOT + k0 + kk8);
        }
        if (k0 < 256) {
            int n = tid & 31;
            int kk8 = (tid >> 5) << 3;
            const float* sp = seed + ((size_t)b * CS + k0 + kk8) * S_ + s0 + n;
            unsigned short tmp[8];
            #pragma unroll
            for (int r = 0; r < 8; ++r)
                tmp[r] = f2bf(sp[(size_t)r * S_]);
            *(short8*)&sB[n][kk8] = *(const short8*)tmp;
        } else {
            int n = tid >> 3;
            int kk8 = (tid & 7) << 3;
            const unsigned short* gp =
                refT + ((size_t)b * NC + sIdx[n]) * C_ + (k0 - 256) + kk8;
            *(short8*)&sB[n][kk8] = *(const short8*)gp;
        }
        __syncthreads();
        #pragma unroll
        for (int kf = 0; kf < 2; ++kf) {
            short8 af[2], bfr[2];
            #pragma unroll
            for (int i = 0; i < 2; ++i)
                af[i] = *(const short8*)&sA[w * 32 + i * 16 + ln][kf * 32 + q8];
            #pragma unroll
            for (int j = 0; j < 2; ++j)
                bfr[j] = *(const short8*)&sB[j * 16 + ln][kf * 32 + q8];
            #pragma unroll
            for (int i = 0; i < 2; ++i)
                #pragma unroll
                for (int j = 0; j < 2; ++j)
                    acc[i][j] = __builtin_amdgcn_mfma_f32_16x16x32_bf16(af[i], bfr[j], acc[i][j], 0, 0, 0);
        }
    }

    #pragma unroll
    for (int i = 0; i < 2; ++i) {
        int mb = w * 32 + i * 16 + quad * 4;
        #pragma unroll
        for (int j = 0; j < 2; ++j) {
            int col = s0 + j * 16 + ln;
            #pragma unroll
            for (int r = 0; r < 4; ++r) {
                int m = mb + r;
                out[((size_t)b * CS + m0 + m) * S_ + col] = acc[i][j][r] + sBias[m];
            }
        }
    }
}

extern "C" void kernel_launch(void* const* d_in, const int* in_sizes, int n_in,
                              void* d_out, int out_size, void* d_ws, size_t ws_size,
                              hipStream_t stream) {
    const float* qxyz  = (const float*)d_in[0];
    const float* rxyz  = (const float*)d_in[1];
    const float* rfeat = (const float*)d_in[2];
    const float* seed  = (const float*)d_in[3];
    const float* Wseed = (const float*)d_in[4];
    const float* bseed = (const float*)d_in[5];
    const float* Wcat  = (const float*)d_in[6];
    const float* bcat  = (const float*)d_in[7];
    float* out = (float*)d_out;

    char* ws = (char*)d_ws;
    float4* refpk         = (float4*)(ws);                       // 2 planes, 1 MB
    int* idxbuf           = (int*)(ws + 1048576);                // 64 KB
    float* beff           = (float*)(ws + 1114112);              // 1 KB
    unsigned short* Wcomb = (unsigned short*)(ws + 1115136);     // 384 KB
    unsigned short* refT  = (unsigned short*)(ws + 1508352);     // 32 MB

    hipLaunchKernelGGL(pad_ref_kernel,    dim3(64),          dim3(256), 0, stream, rxyz, refpk);
    hipLaunchKernelGGL(argmin_kernel,     dim3(128, 4),      dim3(256), 0, stream, qxyz, refpk, idxbuf);
    hipLaunchKernelGGL(transpose_kernel,  dim3(128, 8, 4),   dim3(256), 0, stream, rfeat, refT);
    hipLaunchKernelGGL(wc_kernel,         dim3(8, 4),        dim3(256), 0, stream, Wcat, Wseed, Wcomb);
    hipLaunchKernelGGL(w1_kernel,         dim3(256),         dim3(256), 0, stream, Wcat, Wcomb);
    hipLaunchKernelGGL(beff_kernel,       dim3(1),           dim3(256), 0, stream, Wcat, bseed, bcat, beff);
    hipLaunchKernelGGL(fused_gemm_kernel, dim3(128, 2, 4),   dim3(256), 0, stream,
                       Wcomb, seed, refT, idxbuf, beff, out);
}